// Round 5
// baseline (2802.599 us; speedup 1.0000x reference)
//
#include <hip/hip_runtime.h>

constexpr int NX = 32, NU = 16, NF = 512;
constexpr int SEQ = 2048;
constexpr int CH = 32;          // steps per u-chunk
constexpr int NT = 512;         // threads per block; 2 rows per block, interleaved

__device__ __forceinline__ float fast_tanh(float y) {
    y = fminf(15.f, fmaxf(-15.f, y));
    float e = __expf(2.f * y);
    return (e - 1.f) * __builtin_amdgcn_rcpf(e + 1.f);
}

__global__ __launch_bounds__(NT)
__attribute__((amdgpu_waves_per_eu(2, 2)))   // 1 block/CU anyway (grid=256): take 256-VGPR budget
void fes_kernel(
    const float* __restrict__ x0, const float* __restrict__ ug,
    const float* __restrict__ W1, const float* __restrict__ b1,
    const float* __restrict__ W2, const float* __restrict__ b2,
    float* __restrict__ out)
{
    __shared__ float4 xsA[NX / 4], xsB[NX / 4];     // states (128 B each)
    __shared__ float4 hsA[NF / 4], hsB[NF / 4];     // activations (2 KB each)
    __shared__ float4 usA[CH][NU / 4], usB[CH][NU / 4]; // u chunks (2 KB each)

    const int tid  = threadIdx.x;
    const int rowA = 2 * blockIdx.x, rowB = rowA + 1;
    const int j = tid >> 4, l = tid & 15;           // GEMM2: 16 lanes per output j

    // ---- persistent registers --------------------------------------------
    float w1c[48];                                  // W1 column, feature f = tid
#pragma unroll
    for (int k = 0; k < 48; ++k) w1c[k] = W1[k * NF + tid];
    const float b1r = b1[tid];

    float w2r[32];                                  // TS-prescaled W2 k-slice
#pragma unroll
    for (int i = 0; i < 8; ++i)
#pragma unroll
        for (int c = 0; c < 4; ++c)
            w2r[i * 4 + c] = 0.01f * W2[(4 * l + 64 * i + c) * NX + j];
    const float s0i = (l == 0) ? 0.01f * b2[j] : 0.f;

    float xregA = x0[rowA * NX + j];
    float xregB = x0[rowB * NX + j];

    const float* ugA  = ug  + (size_t)rowA * SEQ * NU;
    const float* ugB  = ug  + (size_t)rowB * SEQ * NU;
    float*       outA = out + (size_t)rowA * SEQ * NX;
    float*       outB = out + (size_t)rowB * SEQ * NX;

    if (tid < NX)           ((float*)xsA)[tid]      = x0[rowA * NX + tid];
    else if (tid < 2 * NX)  ((float*)xsB)[tid - NX] = x0[rowB * NX + tid - NX];
    __syncthreads();

    // GEMM1 for one row: h = tanh(W1^T [x;u] + b1)
    auto G1 = [&](const float4* xs, const float4* up) -> float {
        float a0 = b1r, a1 = 0.f, a2 = 0.f, a3 = 0.f;
#pragma unroll
        for (int kk = 0; kk < 8; ++kk) {
            const float4 xv = xs[kk];               // wave-uniform broadcast
            a0 = fmaf(w1c[4 * kk],     xv.x, a0);
            a1 = fmaf(w1c[4 * kk + 1], xv.y, a1);
            a2 = fmaf(w1c[4 * kk + 2], xv.z, a2);
            a3 = fmaf(w1c[4 * kk + 3], xv.w, a3);
        }
#pragma unroll
        for (int kk = 0; kk < 4; ++kk) {
            const float4 uv = up[kk];               // wave-uniform broadcast
            a0 = fmaf(w1c[32 + 4 * kk], uv.x, a0);
            a1 = fmaf(w1c[33 + 4 * kk], uv.y, a1);
            a2 = fmaf(w1c[34 + 4 * kk], uv.z, a2);
            a3 = fmaf(w1c[35 + 4 * kk], uv.w, a3);
        }
        return fast_tanh((a0 + a1) + (a2 + a3));
    };

    // GEMM2 for one row: x += TS*(W2^T h + b2)  (TS pre-folded into w2r/s0i)
    auto G2 = [&](const float4* hs, float& xreg) -> float {
        float s0 = s0i, s1 = 0.f, s2 = 0.f, s3 = 0.f;
#pragma unroll
        for (int i = 0; i < 8; ++i) {
            const float4 hv = hs[l + 16 * i];       // 16 lines/wave, broadcast groups
            s0 = fmaf(hv.x, w2r[4 * i],     s0);
            s1 = fmaf(hv.y, w2r[4 * i + 1], s1);
            s2 = fmaf(hv.z, w2r[4 * i + 2], s2);
            s3 = fmaf(hv.w, w2r[4 * i + 3], s3);
        }
        float s = (s0 + s1) + (s2 + s3);
        s += __shfl_xor(s, 1);
        s += __shfl_xor(s, 2);
        s += __shfl_xor(s, 4);
        s += __shfl_xor(s, 8);
        xreg += s;
        return xreg;
    };

    for (int t0 = 0; t0 < SEQ; t0 += CH) {
        // ---- load u chunk for both rows (old chunk dead since last barrier)
        if (tid < 256) {
            const int r = tid >> 7, rem = tid & 127;   // r uniform per wave
            const float* src = (r ? ugB : ugA) + (size_t)t0 * NU + rem * 4;
            ((float4*)(r ? usB : usA))[rem] = *(const float4*)src;
        }
        __syncthreads();

#pragma unroll 1
        for (int tc = 0; tc < CH; ++tc) {
            const int t = t0 + tc;
            // ---- segment 1: G1(A,t) + G2(B,t-1) --------------------------
            const float hA = G1(xsA, usA[tc]);
            if (t > 0) {
                const float xnB = G2(hsB, xregB);
                if (l == 0) {
                    ((float*)xsB)[j] = xnB;
                    outB[(size_t)(t - 1) * NX + j] = xnB;
                }
            }
            ((float*)hsA)[tid] = hA;
            __syncthreads();

            // ---- segment 2: G1(B,t) + G2(A,t) ----------------------------
            const float hB = G1(xsB, usB[tc]);
            const float xnA = G2(hsA, xregA);
            ((float*)hsB)[tid] = hB;
            if (l == 0) {
                ((float*)xsA)[j] = xnA;
                outA[(size_t)t * NX + j] = xnA;
            }
            __syncthreads();
        }
    }

    // ---- epilogue: finish row B's last step ------------------------------
    {
        const float xnB = G2(hsB, xregB);
        if (l == 0) outB[(size_t)(SEQ - 1) * NX + j] = xnB;
    }
}

extern "C" void kernel_launch(void* const* d_in, const int* in_sizes, int n_in,
                              void* d_out, int out_size, void* d_ws, size_t ws_size,
                              hipStream_t stream) {
    const float* x0 = (const float*)d_in[0];
    const float* ug = (const float*)d_in[1];
    const float* W1 = (const float*)d_in[2];
    const float* b1 = (const float*)d_in[3];
    const float* W2 = (const float*)d_in[4];
    const float* b2 = (const float*)d_in[5];
    float* out = (float*)d_out;

    fes_kernel<<<dim3(256), dim3(NT), 0, stream>>>(x0, ug, W1, b1, W2, b2, out);
}

// Round 6
// 1792.250 us; speedup vs baseline: 1.5637x; 1.5637x over previous
//
#include <hip/hip_runtime.h>

constexpr int NX = 32, NU = 16, NF = 512;
constexpr int SEQ = 2048;
constexpr int NT = 256;   // threads per block; 1 row per block; 2 features + 2 outputs per thread

__device__ __forceinline__ float fast_tanh(float y) {
    y = fminf(15.f, fmaxf(-15.f, y));
    float e = __expf(2.f * y);
    return (e - 1.f) * __builtin_amdgcn_rcpf(e + 1.f);
}

// VALU-pipe cross-lane add within rows of 16 (no DS instructions)
template<int CTRL>
__device__ __forceinline__ float dpp_add(float v) {
    int t = __builtin_amdgcn_update_dpp(0, __float_as_int(v), CTRL, 0xF, 0xF, true);
    return v + __int_as_float(t);
}
// CTRL: 0xB1 = quad_perm(1,0,3,2)=xor1, 0x4E = quad_perm(2,3,0,1)=xor2,
//       0x124 = row_ror:4, 0x128 = row_ror:8  -> full 16-lane all-reduce

__global__ __launch_bounds__(NT, 2)   // VGPR cap 256, 2 blocks/CU
void fes_kernel(const float* __restrict__ x0, const float* __restrict__ ug,
                const float* __restrict__ W1, const float* __restrict__ b1,
                const float* __restrict__ W2, const float* __restrict__ b2,
                float* __restrict__ out)
{
    __shared__ float4 xs4[NX / 4];    // state, 128 B
    __shared__ float4 hs4[NF / 4];    // activations, 2 KB

    const int tid = threadIdx.x;
    const int row = blockIdx.x;
    const int f1  = tid + NT;         // second feature
    const int sl  = tid >> 4;         // slot -> j0
    const int l   = tid & 15;         // k-split lane within slot
    const int j0  = sl, j1 = sl + 16; // two outputs per thread

    // ---- persistent registers --------------------------------------------
    float w1a[48], w1b[48];           // W1 columns for features tid, tid+256
#pragma unroll
    for (int k = 0; k < 48; ++k) {
        w1a[k] = W1[k * NF + tid];
        w1b[k] = W1[k * NF + f1];
    }
    const float b1a = b1[tid], b1b = b1[f1];

    float w2a[32], w2b[32];           // TS-prescaled W2 k-slices for j0, j1
#pragma unroll
    for (int i = 0; i < 8; ++i)
#pragma unroll
        for (int c = 0; c < 4; ++c) {
            const int f = 4 * (l + 16 * i) + c;
            w2a[4 * i + c] = 0.01f * W2[f * NX + j0];
            w2b[4 * i + c] = 0.01f * W2[f * NX + j1];
        }
    const float bb0 = 0.01f * b2[j0], bb1 = 0.01f * b2[j1];

    float xr0 = x0[row * NX + j0];
    float xr1 = x0[row * NX + j1];

    const float4* ug4    = (const float4*)(ug + (size_t)row * SEQ * NU);  // 4 float4 per step
    float*        out_row = out + (size_t)row * SEQ * NX;

    if (tid < NX / 4) xs4[tid] = ((const float4*)(x0 + row * NX))[tid];

    // prefetch u[0] into registers (wave-uniform address -> scalar/L1 path)
    float4 u0 = ug4[0], u1 = ug4[1], u2 = ug4[2], u3 = ug4[3];
    __syncthreads();

    for (int t = 0; t < SEQ; ++t) {
        // ---- G1: h[f] = tanh(W1^T [x;u] + b1) for f = tid, tid+256 -------
        float p0 = b1a, p1 = 0.f, p2 = 0.f, p3 = 0.f;
        float q0 = b1b, q1 = 0.f, q2 = 0.f, q3 = 0.f;
#pragma unroll
        for (int kk = 0; kk < 8; ++kk) {
            const float4 xv = xs4[kk];                 // broadcast read, reused 2x
            p0 = fmaf(w1a[4*kk],   xv.x, p0);
            p1 = fmaf(w1a[4*kk+1], xv.y, p1);
            p2 = fmaf(w1a[4*kk+2], xv.z, p2);
            p3 = fmaf(w1a[4*kk+3], xv.w, p3);
            q0 = fmaf(w1b[4*kk],   xv.x, q0);
            q1 = fmaf(w1b[4*kk+1], xv.y, q1);
            q2 = fmaf(w1b[4*kk+2], xv.z, q2);
            q3 = fmaf(w1b[4*kk+3], xv.w, q3);
        }
        // u part from registers (no LDS)
        p0 = fmaf(w1a[32], u0.x, p0); p1 = fmaf(w1a[33], u0.y, p1);
        p2 = fmaf(w1a[34], u0.z, p2); p3 = fmaf(w1a[35], u0.w, p3);
        p0 = fmaf(w1a[36], u1.x, p0); p1 = fmaf(w1a[37], u1.y, p1);
        p2 = fmaf(w1a[38], u1.z, p2); p3 = fmaf(w1a[39], u1.w, p3);
        p0 = fmaf(w1a[40], u2.x, p0); p1 = fmaf(w1a[41], u2.y, p1);
        p2 = fmaf(w1a[42], u2.z, p2); p3 = fmaf(w1a[43], u2.w, p3);
        p0 = fmaf(w1a[44], u3.x, p0); p1 = fmaf(w1a[45], u3.y, p1);
        p2 = fmaf(w1a[46], u3.z, p2); p3 = fmaf(w1a[47], u3.w, p3);
        q0 = fmaf(w1b[32], u0.x, q0); q1 = fmaf(w1b[33], u0.y, q1);
        q2 = fmaf(w1b[34], u0.z, q2); q3 = fmaf(w1b[35], u0.w, q3);
        q0 = fmaf(w1b[36], u1.x, q0); q1 = fmaf(w1b[37], u1.y, q1);
        q2 = fmaf(w1b[38], u1.z, q2); q3 = fmaf(w1b[39], u1.w, q3);
        q0 = fmaf(w1b[40], u2.x, q0); q1 = fmaf(w1b[41], u2.y, q1);
        q2 = fmaf(w1b[42], u2.z, q2); q3 = fmaf(w1b[43], u2.w, q3);
        q0 = fmaf(w1b[44], u3.x, q0); q1 = fmaf(w1b[45], u3.y, q1);
        q2 = fmaf(w1b[46], u3.z, q2); q3 = fmaf(w1b[47], u3.w, q3);

        const float h0 = fast_tanh((p0 + p1) + (p2 + p3));
        const float h1 = fast_tanh((q0 + q1) + (q2 + q3));
        ((float*)hs4)[tid] = h0;                       // 2x ds_write_b32, 2-way banks (free)
        ((float*)hs4)[f1]  = h1;

        // prefetch next step's u (hidden under G2)
        const int tn = (t + 1 < SEQ) ? t + 1 : t;
        const float4 n0 = ug4[4 * tn];
        const float4 n1 = ug4[4 * tn + 1];
        const float4 n2 = ug4[4 * tn + 2];
        const float4 n3 = ug4[4 * tn + 3];
        __syncthreads();

        // ---- G2: dx[j] for j0, j1; 16-lane k-split, DPP reduce -----------
        float sa0 = 0.f, sa1 = 0.f, sa2 = 0.f, sa3 = 0.f;
        float sb0 = 0.f, sb1 = 0.f, sb2 = 0.f, sb3 = 0.f;
        const float* hsp = (const float*)hs4;
#pragma unroll
        for (int i = 0; i < 8; ++i) {
            const float4 hv = *(const float4*)&hsp[4 * (l + 16 * i)];  // reused 2x
            sa0 = fmaf(hv.x, w2a[4*i],   sa0);
            sa1 = fmaf(hv.y, w2a[4*i+1], sa1);
            sa2 = fmaf(hv.z, w2a[4*i+2], sa2);
            sa3 = fmaf(hv.w, w2a[4*i+3], sa3);
            sb0 = fmaf(hv.x, w2b[4*i],   sb0);
            sb1 = fmaf(hv.y, w2b[4*i+1], sb1);
            sb2 = fmaf(hv.z, w2b[4*i+2], sb2);
            sb3 = fmaf(hv.w, w2b[4*i+3], sb3);
        }
        float sa = (sa0 + sa1) + (sa2 + sa3);
        float sb = (sb0 + sb1) + (sb2 + sb3);
        sa = dpp_add<0xB1>(sa);   sb = dpp_add<0xB1>(sb);    // xor1
        sa = dpp_add<0x4E>(sa);   sb = dpp_add<0x4E>(sb);    // xor2
        sa = dpp_add<0x124>(sa);  sb = dpp_add<0x124>(sb);   // ror4
        sa = dpp_add<0x128>(sa);  sb = dpp_add<0x128>(sb);   // ror8

        const float xn0 = xr0 + (sa + bb0);
        const float xn1 = xr1 + (sb + bb1);
        xr0 = xn0; xr1 = xn1;
        if (l == 0) {
            ((float*)xs4)[j0] = xn0;
            ((float*)xs4)[j1] = xn1;
            out_row[(size_t)t * NX + j0] = xn0;
            out_row[(size_t)t * NX + j1] = xn1;
        }
        u0 = n0; u1 = n1; u2 = n2; u3 = n3;
        __syncthreads();
    }
}

extern "C" void kernel_launch(void* const* d_in, const int* in_sizes, int n_in,
                              void* d_out, int out_size, void* d_ws, size_t ws_size,
                              hipStream_t stream) {
    const float* x0 = (const float*)d_in[0];
    const float* ug = (const float*)d_in[1];
    const float* W1 = (const float*)d_in[2];
    const float* b1 = (const float*)d_in[3];
    const float* W2 = (const float*)d_in[4];
    const float* b2 = (const float*)d_in[5];
    float* out = (float*)d_out;

    fes_kernel<<<dim3(512), dim3(NT), 0, stream>>>(x0, ug, W1, b1, W2, b2, out);
}

// Round 7
// 1746.593 us; speedup vs baseline: 1.6046x; 1.0261x over previous
//
#include <hip/hip_runtime.h>

constexpr int NX = 32, NU = 16, NF = 512;
constexpr int SEQ = 2048;
constexpr int CH = 32;            // steps per u-chunk
constexpr int NT = 256;           // 1 row/block; 4 feat (k-split 2) + 2 outputs per thread
constexpr float SC = 2.88539008177792681f;   // 2/ln2: tanh(a) = 1 - 2/(exp2(SC*a)+1)

// VALU-pipe cross-lane add (no DS instructions)
template<int CTRL>
__device__ __forceinline__ float dpp_add(float v) {
    int t = __builtin_amdgcn_update_dpp(0, __float_as_int(v), CTRL, 0xF, 0xF, true);
    return v + __int_as_float(t);
}
// 0xB1 quad_perm xor1 | 0x4E quad_perm xor2 | 0x124 row_ror:4 | 0x128 row_ror:8

__device__ __forceinline__ float tanh4(float y) {       // y pre-scaled by SC
    const float e = __builtin_amdgcn_exp2f(y);          // +inf/0 both fine
    const float r = __builtin_amdgcn_rcpf(e + 1.f);
    return fmaf(-2.f, r, 1.f);
}

__global__ __launch_bounds__(NT, 2)   // 2 waves/EU -> 256-VGPR budget, 2 blocks/CU
void fes_kernel(const float* __restrict__ x0, const float* __restrict__ ug,
                const float* __restrict__ W1, const float* __restrict__ b1,
                const float* __restrict__ W2, const float* __restrict__ b2,
                float* __restrict__ out)
{
    __shared__ float4 xs4[NX / 4];        // state (8 f4)
    __shared__ float4 hs4[NF / 4];        // activations (128 f4)
    __shared__ float4 us4[CH * NU / 4];   // u chunk (128 f4)

    const int tid = threadIdx.x, row = blockIdx.x;
    const int g   = tid >> 1, kh = tid & 1;        // feature group (4 feats), k-half
    const int sl  = tid >> 4, l  = tid & 15;       // G2: 16 lanes per output
    const int j0  = sl, j1 = sl + 16;

    // ---- persistent registers --------------------------------------------
    // G1: 4 features (4g..4g+3) x 24-input half (kh), prescaled by SC: 96 regs
    float w1r[96];
#pragma unroll
    for (int i = 0; i < 24; ++i)
#pragma unroll
        for (int c = 0; c < 4; ++c)
            w1r[i * 4 + c] = SC * W1[(kh * 24 + i) * NF + 4 * g + c];
    float b1s[4];
#pragma unroll
    for (int c = 0; c < 4; ++c) b1s[c] = kh ? 0.f : SC * b1[4 * g + c];

    // G2: TS-prescaled W2 k-slices for j0, j1 (32 k each): 64 regs
    float w2a[32], w2b[32];
#pragma unroll
    for (int i = 0; i < 8; ++i)
#pragma unroll
        for (int c = 0; c < 4; ++c) {
            const int f = 4 * (l + 16 * i) + c;
            w2a[4 * i + c] = 0.01f * W2[f * NX + j0];
            w2b[4 * i + c] = 0.01f * W2[f * NX + j1];
        }
    const float bb0 = 0.01f * b2[j0], bb1 = 0.01f * b2[j1];

    float xr0 = x0[row * NX + j0];
    float xr1 = x0[row * NX + j1];

    const float* ug_row  = ug  + (size_t)row * SEQ * NU;
    float*       out_row = out + (size_t)row * SEQ * NX;

    if (tid < NX / 4) xs4[tid] = ((const float4*)(x0 + row * NX))[tid];

    // static G1 read base for f4 slots 0..1 (klow: x[0..7], khigh: x[24..31])
    const float4* bA = kh ? xs4 + 6 : xs4;

    for (int t0 = 0; t0 < SEQ; t0 += CH) {
        // ---- stage u chunk (2 KB contiguous) -----------------------------
        if (tid < CH * NU / 4)
            us4[tid] = *(const float4*)&ug_row[(size_t)t0 * NU + tid * 4];
        __syncthreads();   // also covers xs init on first iter

#pragma unroll 1
        for (int tc = 0; tc < CH; ++tc) {
            const int t = t0 + tc;
            // ---- G1: half-dots for 4 features (6 x ds_read_b128) ---------
            // klow: inputs 0..23 = x f4 0..5 ; khigh: inputs 24..47 = x f4 6,7 + u f4 0..3
            const float4* bB = kh ? us4 + tc * 4 - 2 : xs4;
            const float4 iv0 = bA[0], iv1 = bA[1];
            const float4 iv2 = bB[2], iv3 = bB[3], iv4 = bB[4], iv5 = bB[5];
            float a0 = b1s[0], a1 = b1s[1], a2 = b1s[2], a3 = b1s[3];
#define G1F4(iv, q)                                                        \
            a0 = fmaf(w1r[(q)*16 + 0],  iv.x, a0);                         \
            a1 = fmaf(w1r[(q)*16 + 1],  iv.x, a1);                         \
            a2 = fmaf(w1r[(q)*16 + 2],  iv.x, a2);                         \
            a3 = fmaf(w1r[(q)*16 + 3],  iv.x, a3);                         \
            a0 = fmaf(w1r[(q)*16 + 4],  iv.y, a0);                         \
            a1 = fmaf(w1r[(q)*16 + 5],  iv.y, a1);                         \
            a2 = fmaf(w1r[(q)*16 + 6],  iv.y, a2);                         \
            a3 = fmaf(w1r[(q)*16 + 7],  iv.y, a3);                         \
            a0 = fmaf(w1r[(q)*16 + 8],  iv.z, a0);                         \
            a1 = fmaf(w1r[(q)*16 + 9],  iv.z, a1);                         \
            a2 = fmaf(w1r[(q)*16 + 10], iv.z, a2);                         \
            a3 = fmaf(w1r[(q)*16 + 11], iv.z, a3);                         \
            a0 = fmaf(w1r[(q)*16 + 12], iv.w, a0);                         \
            a1 = fmaf(w1r[(q)*16 + 13], iv.w, a1);                         \
            a2 = fmaf(w1r[(q)*16 + 14], iv.w, a2);                         \
            a3 = fmaf(w1r[(q)*16 + 15], iv.w, a3);
            G1F4(iv0, 0) G1F4(iv1, 1) G1F4(iv2, 2)
            G1F4(iv3, 3) G1F4(iv4, 4) G1F4(iv5, 5)
#undef G1F4
            // pair-sum (k-split 2) via quad_perm xor1
            a0 = dpp_add<0xB1>(a0);
            a1 = dpp_add<0xB1>(a1);
            a2 = dpp_add<0xB1>(a2);
            a3 = dpp_add<0xB1>(a3);
            // split the 4 tanh across the pair; write h as one b64 each
            float2 hw;
            hw.x = tanh4(kh ? a2 : a0);
            hw.y = tanh4(kh ? a3 : a1);
            ((float2*)hs4)[g * 2 + kh] = hw;
            __syncthreads();

            // ---- G2: dx for j0, j1 (8 x ds_read_b128, DPP reduce) --------
            float sa0 = 0.f, sa1 = 0.f, sa2 = 0.f, sa3 = 0.f;
            float sb0 = 0.f, sb1 = 0.f, sb2 = 0.f, sb3 = 0.f;
#pragma unroll
            for (int i = 0; i < 8; ++i) {
                const float4 hv = hs4[l + 16 * i];
                sa0 = fmaf(hv.x, w2a[4*i],   sa0);
                sa1 = fmaf(hv.y, w2a[4*i+1], sa1);
                sa2 = fmaf(hv.z, w2a[4*i+2], sa2);
                sa3 = fmaf(hv.w, w2a[4*i+3], sa3);
                sb0 = fmaf(hv.x, w2b[4*i],   sb0);
                sb1 = fmaf(hv.y, w2b[4*i+1], sb1);
                sb2 = fmaf(hv.z, w2b[4*i+2], sb2);
                sb3 = fmaf(hv.w, w2b[4*i+3], sb3);
            }
            float sa = (sa0 + sa1) + (sa2 + sa3);
            float sb = (sb0 + sb1) + (sb2 + sb3);
            sa = dpp_add<0xB1>(sa);   sb = dpp_add<0xB1>(sb);
            sa = dpp_add<0x4E>(sa);   sb = dpp_add<0x4E>(sb);
            sa = dpp_add<0x124>(sa);  sb = dpp_add<0x124>(sb);
            sa = dpp_add<0x128>(sa);  sb = dpp_add<0x128>(sb);

            const float xn0 = xr0 + (sa + bb0);
            const float xn1 = xr1 + (sb + bb1);
            xr0 = xn0; xr1 = xn1;
            if (l < 2) {                       // 2 lanes share the 2 stores
                const float v  = l ? xn1 : xn0;
                const int   jj = j0 + (l << 4);
                ((float*)xs4)[jj] = v;
                out_row[(size_t)t * NX + jj] = v;
            }
            __syncthreads();
        }
    }
}

extern "C" void kernel_launch(void* const* d_in, const int* in_sizes, int n_in,
                              void* d_out, int out_size, void* d_ws, size_t ws_size,
                              hipStream_t stream) {
    const float* x0 = (const float*)d_in[0];
    const float* ug = (const float*)d_in[1];
    const float* W1 = (const float*)d_in[2];
    const float* b1 = (const float*)d_in[3];
    const float* W2 = (const float*)d_in[4];
    const float* b2 = (const float*)d_in[5];
    float* out = (float*)d_out;

    fes_kernel<<<dim3(512), dim3(NT), 0, stream>>>(x0, ug, W1, b1, W2, b2, out);
}

// Round 8
// 1719.132 us; speedup vs baseline: 1.6302x; 1.0160x over previous
//
#include <hip/hip_runtime.h>

typedef float v2f __attribute__((ext_vector_type(2)));

constexpr int NX = 32, NU = 16, NF = 512;
constexpr int SEQ = 2048;
constexpr int CH = 32;            // steps per u-chunk
constexpr int NT = 256;           // 1 row/block
constexpr float SC = 2.88539008177792681f;   // 2/ln2: tanh(a) = 1 - 2/(exp2(SC*a)+1)

// VALU-pipe cross-lane add (no DS instructions)
template<int CTRL>
__device__ __forceinline__ float dpp_add(float v) {
    int t = __builtin_amdgcn_update_dpp(0, __float_as_int(v), CTRL, 0xF, 0xF, true);
    return v + __int_as_float(t);
}
// 0xB1 xor1 | 0x4E xor2 | 0x124 row_ror:4 | 0x128 row_ror:8 | 0x142 row_bcast15

__device__ __forceinline__ float tanh4(float y) {       // y pre-scaled by SC
    const float e = __builtin_amdgcn_exp2f(y);
    const float r = __builtin_amdgcn_rcpf(e + 1.f);
    return fmaf(-2.f, r, 1.f);
}

__device__ __forceinline__ v2f pkfma(v2f a, v2f b, v2f c) { return a * b + c; }

__global__ __launch_bounds__(NT, 2)   // 2 waves/EU -> 256-VGPR budget, 2 blocks/CU
void fes_kernel(const float* __restrict__ x0, const float* __restrict__ ug,
                const float* __restrict__ W1, const float* __restrict__ b1,
                const float* __restrict__ W2, const float* __restrict__ b2,
                float* __restrict__ out)
{
    __shared__ float4 xs4[NX / 4];        // state (8 f4)
    __shared__ float4 hs4[NF / 4];        // activations (128 f4)
    __shared__ float4 us4[CH * NU / 4];   // u chunk (128 f4)

    const int tid = threadIdx.x, row = blockIdx.x;
    const int lam = tid & 63, w = tid >> 6;
    // G1 (round-7 verified map): feature quad g, k-half kh
    const int g = tid >> 1, kh = tid & 1;
    // G2: k-split 32, strided slices; output f4-set os; owners = lanes 31/63
    const int sk = (lam & 15) | (((lam >> 4) & 1) << 4);
    const int os = ((lam >> 5) & 1) + 2 * w;
    const bool owner = (lam & 31) == 31;

    // ---- persistent registers --------------------------------------------
    // G1 weights as k-parity pairs: wk[i*12+kp] = SC*{W1[24kh+2kp][4g+i], W1[+1][4g+i]}
    v2f wk[48];
#pragma unroll
    for (int i = 0; i < 4; ++i)
#pragma unroll
        for (int kp = 0; kp < 12; ++kp) {
            const int k = 24 * kh + 2 * kp;
            wk[i * 12 + kp] = v2f{SC * W1[k * NF + 4 * g + i],
                                  SC * W1[(k + 1) * NF + 4 * g + i]};
        }
    const float b1e = SC * b1[4 * g + 2 * kh];
    const float b1o = SC * b1[4 * g + 2 * kh + 1];

    // G2 weights: wc[c][2m+p] = TS*{W2[128m+4sk+2p][4os+c], W2[k+1][4os+c]}
    v2f wc[4][8];
#pragma unroll
    for (int c = 0; c < 4; ++c)
#pragma unroll
        for (int m = 0; m < 4; ++m)
#pragma unroll
            for (int p = 0; p < 2; ++p) {
                const int k = 128 * m + 4 * sk + 2 * p;
                wc[c][2 * m + p] = v2f{0.01f * W2[k * NX + 4 * os + c],
                                       0.01f * W2[(k + 1) * NX + 4 * os + c]};
            }
    float bb0 = 0.01f * b2[4 * os + 0], bb1 = 0.01f * b2[4 * os + 1];
    float bb2 = 0.01f * b2[4 * os + 2], bb3 = 0.01f * b2[4 * os + 3];
    float xr0 = x0[row * NX + 4 * os + 0], xr1 = x0[row * NX + 4 * os + 1];
    float xr2 = x0[row * NX + 4 * os + 2], xr3 = x0[row * NX + 4 * os + 3];

    const float* ug_row  = ug  + (size_t)row * SEQ * NU;
    float*       out_row = out + (size_t)row * SEQ * NX;

    if (tid < NX / 4) xs4[tid] = ((const float4*)(x0 + row * NX))[tid];

    // G1 read bases: klow: x f4 0..5 ; khigh: x f4 6,7 then u f4 0..3
    const float4* bA = kh ? xs4 + 6 : xs4;
    const float4* hp = hs4 + sk;          // G2 base: reads hp[0,32,64,96]

    for (int t0 = 0; t0 < SEQ; t0 += CH) {
        if (tid < CH * NU / 4)
            us4[tid] = *(const float4*)&ug_row[(size_t)t0 * NU + tid * 4];
        __syncthreads();   // covers xs init on first iter, u-chunk always

#pragma unroll 1
        for (int tc = 0; tc < CH; ++tc) {
            const int t = t0 + tc;
            // ---- G1: 4 features (4g..4g+3), k-half kh, pk-paired ---------
            const float4* bB = kh ? us4 + 4 * tc - 2 : xs4;
            const float4 iv0 = bA[0], iv1 = bA[1];
            const float4 iv2 = bB[2], iv3 = bB[3], iv4 = bB[4], iv5 = bB[5];
            v2f a0 = {0.f, 0.f}, a1 = {0.f, 0.f}, a2 = {0.f, 0.f}, a3 = {0.f, 0.f};
#define G1S(iv, s)                                                          \
            {   const v2f lo = {iv.x, iv.y}, hi = {iv.z, iv.w};             \
                a0 = pkfma(wk[0*12 + 2*(s)], lo, a0);                       \
                a1 = pkfma(wk[1*12 + 2*(s)], lo, a1);                       \
                a2 = pkfma(wk[2*12 + 2*(s)], lo, a2);                       \
                a3 = pkfma(wk[3*12 + 2*(s)], lo, a3);                       \
                a0 = pkfma(wk[0*12 + 2*(s) + 1], hi, a0);                   \
                a1 = pkfma(wk[1*12 + 2*(s) + 1], hi, a1);                   \
                a2 = pkfma(wk[2*12 + 2*(s) + 1], hi, a2);                   \
                a3 = pkfma(wk[3*12 + 2*(s) + 1], hi, a3); }
            G1S(iv0, 0) G1S(iv1, 1) G1S(iv2, 2) G1S(iv3, 3) G1S(iv4, 4) G1S(iv5, 5)
#undef G1S
            float h0 = a0.x + a0.y, h1 = a1.x + a1.y;
            float h2 = a2.x + a2.y, h3 = a3.x + a3.y;
            h0 = dpp_add<0xB1>(h0);  h1 = dpp_add<0xB1>(h1);   // join k-halves
            h2 = dpp_add<0xB1>(h2);  h3 = dpp_add<0xB1>(h3);
            const float he = kh ? h2 : h0, ho = kh ? h3 : h1;
            float2 hw;
            hw.x = tanh4(he + b1e);
            hw.y = tanh4(ho + b1o);
            ((float2*)hs4)[2 * g + kh] = hw;     // feature floats 4g+2kh, +1
            __syncthreads();

            // ---- G2: 4 outputs (4os..4os+3), strided k-slice, pk-paired --
            v2f A0 = {0.f, 0.f}, A1 = {0.f, 0.f}, A2 = {0.f, 0.f}, A3 = {0.f, 0.f};
#pragma unroll
            for (int m = 0; m < 4; ++m) {
                const float4 hv = hp[32 * m];    // 32 seq 16B addrs: conflict-free
                const v2f lo = {hv.x, hv.y}, hi = {hv.z, hv.w};
                A0 = pkfma(wc[0][2 * m], lo, A0);
                A1 = pkfma(wc[1][2 * m], lo, A1);
                A2 = pkfma(wc[2][2 * m], lo, A2);
                A3 = pkfma(wc[3][2 * m], lo, A3);
                A0 = pkfma(wc[0][2 * m + 1], hi, A0);
                A1 = pkfma(wc[1][2 * m + 1], hi, A1);
                A2 = pkfma(wc[2][2 * m + 1], hi, A2);
                A3 = pkfma(wc[3][2 * m + 1], hi, A3);
            }
            float s0 = A0.x + A0.y, s1 = A1.x + A1.y;
            float s2 = A2.x + A2.y, s3 = A3.x + A3.y;
            // 16-lane all-reduce, then row_bcast15 joins row pairs (lanes 31/63 valid)
            s0 = dpp_add<0xB1>(s0);  s1 = dpp_add<0xB1>(s1);
            s2 = dpp_add<0xB1>(s2);  s3 = dpp_add<0xB1>(s3);
            s0 = dpp_add<0x4E>(s0);  s1 = dpp_add<0x4E>(s1);
            s2 = dpp_add<0x4E>(s2);  s3 = dpp_add<0x4E>(s3);
            s0 = dpp_add<0x124>(s0); s1 = dpp_add<0x124>(s1);
            s2 = dpp_add<0x124>(s2); s3 = dpp_add<0x124>(s3);
            s0 = dpp_add<0x128>(s0); s1 = dpp_add<0x128>(s1);
            s2 = dpp_add<0x128>(s2); s3 = dpp_add<0x128>(s3);
            s0 = dpp_add<0x142>(s0); s1 = dpp_add<0x142>(s1);
            s2 = dpp_add<0x142>(s2); s3 = dpp_add<0x142>(s3);

            const float xn0 = xr0 + (s0 + bb0);
            const float xn1 = xr1 + (s1 + bb1);
            const float xn2 = xr2 + (s2 + bb2);
            const float xn3 = xr3 + (s3 + bb3);
            xr0 = xn0; xr1 = xn1; xr2 = xn2; xr3 = xn3;
            if (owner) {
                const float4 xv = {xn0, xn1, xn2, xn3};
                xs4[os] = xv;
                *(float4*)&out_row[(size_t)t * NX + 4 * os] = xv;
            }
            __syncthreads();
        }
    }
}

extern "C" void kernel_launch(void* const* d_in, const int* in_sizes, int n_in,
                              void* d_out, int out_size, void* d_ws, size_t ws_size,
                              hipStream_t stream) {
    const float* x0 = (const float*)d_in[0];
    const float* ug = (const float*)d_in[1];
    const float* W1 = (const float*)d_in[2];
    const float* b1 = (const float*)d_in[3];
    const float* W2 = (const float*)d_in[4];
    const float* b2 = (const float*)d_in[5];
    float* out = (float*)d_out;

    fes_kernel<<<dim3(512), dim3(NT), 0, stream>>>(x0, ug, W1, b1, W2, b2, out);
}

// Round 10
// 1711.580 us; speedup vs baseline: 1.6374x; 1.0044x over previous
//
#include <hip/hip_runtime.h>

typedef float v2f __attribute__((ext_vector_type(2)));

constexpr int NX = 32, NU = 16, NF = 512;
constexpr int SEQ = 2048;
constexpr int NT = 256;           // 1 row/block; 2 features per thread, end-to-end
constexpr float SC  = 2.88539008177792681f;  // 2/ln2: tanh(a) = 1 - 2/(exp2(SC*a)+1)
constexpr float TSC = 0.01f;

// read partner-lane value via DPP (VALU pipe, no DS instructions)
template<int CTRL>
__device__ __forceinline__ float dpp_mov(float v) {
    return __int_as_float(__builtin_amdgcn_update_dpp(0, __float_as_int(v), CTRL, 0xF, 0xF, true));
}
// 0xB1 quad_perm xor1 | 0x4E quad_perm xor2 | 0x128 row_ror:8 (= xor8 within 16)

__device__ __forceinline__ float tanh4(float y) {       // y pre-scaled by SC
    const float e = __builtin_amdgcn_exp2f(y);
    const float r = __builtin_amdgcn_rcpf(e + 1.f);
    return fmaf(-2.f, r, 1.f);
}

__global__ __launch_bounds__(NT)
__attribute__((amdgpu_waves_per_eu(2, 2)))   // 256-VGPR budget, 2 waves/SIMD (2 blocks/CU)
void fes_kernel(const float* __restrict__ x0, const float* __restrict__ ug,
                const float* __restrict__ W1, const float* __restrict__ b1,
                const float* __restrict__ W2, const float* __restrict__ b2,
                float* __restrict__ out)
{
    __shared__ __align__(16) float xs_w[4][NX];     // per-wave private state copies
    __shared__ __align__(16) float part[2][NX][4];  // ping-pong cross-wave partials

    const int tid = threadIdx.x, row = blockIdx.x;
    const int l = tid & 63, w = tid >> 6;

    // reduce-scatter permutation: lane l ends owning j = pi(l)
    // XOR-linear: pi(a^b)=pi(a)^pi(b); level constants c_d = pi(d)
    // d=1 -> 16, d=2 -> 8, d=8 -> 4, d=16 -> 2, d=32 -> 1, d=4 -> 0 (duplicate pair)
    const int pi = ((l & 1) << 4) | (((l >> 1) & 1) << 3) | (((l >> 3) & 1) << 2)
                 | (((l >> 4) & 1) << 1) | ((l >> 5) & 1);
    const bool jown = (l & 4) == 0;                 // one writer per j per wave

    const int f0 = 2 * tid, f1 = f0 + 1;            // this thread's two features

    // ---- persistent registers --------------------------------------------
    // G1 weights as k-parity pairs (96 regs)
    v2f wkA[24], wkB[24];
#pragma unroll
    for (int p = 0; p < 24; ++p) {
        wkA[p] = v2f{SC * W1[(2 * p) * NF + f0], SC * W1[(2 * p + 1) * NF + f0]};
        wkB[p] = v2f{SC * W1[(2 * p) * NF + f1], SC * W1[(2 * p + 1) * NF + f1]};
    }
    const float b1A = SC * b1[f0], b1B = SC * b1[f1];

    // G2 weights in the pi domain: position p holds j = p ^ pi  (64 regs)
    v2f wcA[16], wcB[16];
#pragma unroll
    for (int m = 0; m < 16; ++m) {
        wcA[m] = v2f{TSC * W2[f0 * NX + ((2 * m) ^ pi)], TSC * W2[f0 * NX + ((2 * m + 1) ^ pi)]};
        wcB[m] = v2f{TSC * W2[f1 * NX + ((2 * m) ^ pi)], TSC * W2[f1 * NX + ((2 * m + 1) ^ pi)]};
    }
    const float bb = TSC * b2[pi];
    float xr = x0[row * NX + pi];                   // lane-resident state element

    const float* ug_row  = ug  + (size_t)row * SEQ * NU;
    float*       out_row = out + (size_t)row * SEQ * NX;

    if (jown) xs_w[w][pi] = xr;                     // wave-private: no barrier needed
    float4 u0 = *(const float4*)(ug_row + 0);
    float4 u1 = *(const float4*)(ug_row + 4);
    float4 u2 = *(const float4*)(ug_row + 8);
    float4 u3 = *(const float4*)(ug_row + 12);

    const float4* xsr = (const float4*)xs_w[w];

#pragma unroll 1
    for (int t = 0; t < SEQ; ++t) {
        // ---- G1: full 48-dots for f0, f1 (8 uniform b128 + reg u) --------
        v2f aA0 = {b1A, 0.f}, aA1 = {0.f, 0.f};
        v2f aB0 = {b1B, 0.f}, aB1 = {0.f, 0.f};
#pragma unroll
        for (int s = 0; s < 8; ++s) {
            const float4 iv = xsr[s];               // wave-uniform broadcast
            const v2f lo = {iv.x, iv.y}, hi = {iv.z, iv.w};
            aA0 += wkA[2 * s] * lo;  aA1 += wkA[2 * s + 1] * hi;
            aB0 += wkB[2 * s] * lo;  aB1 += wkB[2 * s + 1] * hi;
        }
#define UPART(uv, p0)                                                       \
        { const v2f lo = {uv.x, uv.y}, hi = {uv.z, uv.w};                   \
          aA0 += wkA[p0] * lo;  aA1 += wkA[p0 + 1] * hi;                    \
          aB0 += wkB[p0] * lo;  aB1 += wkB[p0 + 1] * hi; }
        UPART(u0, 16) UPART(u1, 18) UPART(u2, 20) UPART(u3, 22)
#undef UPART
        // prefetch next u (hidden under G2 + reduce + barrier)
        {
            const int tn = (t + 1 < SEQ) ? t + 1 : SEQ - 1;
            const float* un = ug_row + (size_t)tn * NU;
            u0 = *(const float4*)(un + 0);
            u1 = *(const float4*)(un + 4);
            u2 = *(const float4*)(un + 8);
            u3 = *(const float4*)(un + 12);
        }
        const float h0 = tanh4((aA0.x + aA0.y) + (aA1.x + aA1.y));
        const float h1 = tanh4((aB0.x + aB0.y) + (aB1.x + aB1.y));

        // ---- G2: in-register, pi-permuted (32 pk-fma) --------------------
        const v2f h0v = {h0, h0}, h1v = {h1, h1};
        v2f q[16];
#pragma unroll
        for (int m = 0; m < 16; ++m)
            q[m] = h0v * wcA[m] + h1v * wcB[m];

        // ---- reduce-scatter over 64 lanes (31 adds: 28 DPP + 3 shfl) -----
        // level d=1 (c=16): keep p<16, add partner's p^16
#pragma unroll
        for (int m = 0; m < 8; ++m) {
            q[m].x += dpp_mov<0xB1>(q[m + 8].x);
            q[m].y += dpp_mov<0xB1>(q[m + 8].y);
        }
        // level d=2 (c=8): keep p<8, add partner's p^8
#pragma unroll
        for (int m = 0; m < 4; ++m) {
            q[m].x += dpp_mov<0x4E>(q[m + 4].x);
            q[m].y += dpp_mov<0x4E>(q[m + 4].y);
        }
        // level d=8 (c=4): keep p<4, add partner's p^4
#pragma unroll
        for (int m = 0; m < 2; ++m) {
            q[m].x += dpp_mov<0x128>(q[m + 2].x);
            q[m].y += dpp_mov<0x128>(q[m + 2].y);
        }
        // level d=16 (c=2): keep p<2, add partner's p^2
        q[0].x += __shfl_xor(q[1].x, 16);
        q[0].y += __shfl_xor(q[1].y, 16);
        // level d=32 (c=1): keep p=0, add partner's p^1
        q[0].x += __shfl_xor(q[0].y, 32);
        // level d=4 (c=0): join duplicate pair
        q[0].x += __shfl_xor(q[0].x, 4);
        const float S = q[0].x;                     // wave-partial dx for j = pi(l)

        // ---- cross-wave combine: 1 write, 1 barrier, 1 read --------------
        if (jown) part[t & 1][pi][w] = S;
        __syncthreads();
        const float4 P = *(const float4*)part[t & 1][pi];
        xr += ((P.x + P.y) + (P.z + P.w)) + bb;

        if (jown) xs_w[w][pi] = xr;                 // own wave's copy (lgkm-ordered)
        if (w == 0 && jown) out_row[(size_t)t * NX + pi] = xr;
    }
}

extern "C" void kernel_launch(void* const* d_in, const int* in_sizes, int n_in,
                              void* d_out, int out_size, void* d_ws, size_t ws_size,
                              hipStream_t stream) {
    const float* x0 = (const float*)d_in[0];
    const float* ug = (const float*)d_in[1];
    const float* W1 = (const float*)d_in[2];
    const float* b1 = (const float*)d_in[3];
    const float* W2 = (const float*)d_in[4];
    const float* b2 = (const float*)d_in[5];
    float* out = (float*)d_out;

    fes_kernel<<<dim3(512), dim3(NT), 0, stream>>>(x0, ug, W1, b1, W2, b2, out);
}